// Round 3
// baseline (347.490 us; speedup 1.0000x reference)
//
#include <hip/hip_runtime.h>
#include <stdint.h>

#define NN 32
#define CI 256
#define CO 256
#define HH 56
#define WW 56
#define TPH 58
#define TPW 72
#define CNT (NN*HH*WW)

typedef int i32x4 __attribute__((ext_vector_type(4)));

// async global->LDS 16B (wave-uniform LDS base + lane*16)
__device__ __forceinline__ void gld16(const void* g, void* l) {
    __builtin_amdgcn_global_load_lds(
        (const __attribute__((address_space(1))) void*)(uintptr_t)g,
        (__attribute__((address_space(3))) void*)(uint32_t)(uintptr_t)l,
        16, 0, 0);
}

// ============ 1. fused prep: per-channel partial stats (y<8) + weight quant (y==8)
__global__ void prep_kernel(const float* __restrict__ x,
                            const float* __restrict__ w,
                            double* __restrict__ part,
                            int8_t* __restrict__ wT,
                            float* __restrict__ qscale) {
    __shared__ double dred[8];
    __shared__ float fred[4];
    __shared__ float qsh;
    const int wid = threadIdx.x >> 6, lane = threadIdx.x & 63;

    if (blockIdx.y < 8) {
        // ---- stats over 4 images ----
        const int c = blockIdx.x, sp = blockIdx.y;
        double s = 0.0, ss = 0.0;
        const size_t base = ((size_t)(sp * 4) * CI + c) * 3136;
        for (int idx = threadIdx.x; idx < 4 * 784; idx += 256) {
            int nl = idx / 784, q = idx % 784;
            const float4 v = *(const float4*)(x + base + (size_t)nl * CI * 3136 + q * 4);
            double a = v.x, b = v.y, cc = v.z, d = v.w;
            s  += (a + b) + (cc + d);
            ss += (a * a + b * b) + (cc * cc + d * d);
        }
        for (int off = 32; off > 0; off >>= 1) {
            s  += __shfl_down(s, off, 64);
            ss += __shfl_down(ss, off, 64);
        }
        if (lane == 0) { dred[wid] = s; dred[4 + wid] = ss; }
        __syncthreads();
        if (threadIdx.x == 0) {
            part[(sp * 256 + c) * 2]     = (dred[0] + dred[1]) + (dred[2] + dred[3]);
            part[(sp * 256 + c) * 2 + 1] = (dred[4] + dred[5]) + (dred[6] + dred[7]);
        }
    } else {
        // ---- weight quant: per-co int8, layout [tap][chunk][co][ci64] ----
        const int co = blockIdx.x;
        const float* wp = w + (size_t)co * 2304;
        float v[9], m = 0.f;
#pragma unroll
        for (int it = 0; it < 9; ++it) {
            v[it] = wp[threadIdx.x + it * 256];
            m = fmaxf(m, fabsf(v[it]));
        }
        for (int off = 32; off > 0; off >>= 1) m = fmaxf(m, __shfl_down(m, off, 64));
        if (lane == 0) fred[wid] = m;
        __syncthreads();
        if (threadIdx.x == 0) {
            float mx = fmaxf(fmaxf(fred[0], fred[1]), fmaxf(fred[2], fred[3]));
            float q = (mx > 0.f) ? mx / 127.f : 1.f;
            qsh = q;
            qscale[co] = q;
        }
        __syncthreads();
        const float q = qsh;
#pragma unroll
        for (int it = 0; it < 9; ++it) {
            int idx = threadIdx.x + it * 256;
            int ci = idx / 9, tap = idx % 9;
            int chunk = ci >> 6, cis = ci & 63;
            int iq = __float2int_rn(v[it] / q);
            iq = iq > 127 ? 127 : (iq < -127 ? -127 : iq);
            wT[((size_t)(tap * 4 + chunk) * 256 + co) * 64 + cis] = (int8_t)iq;
        }
    }
}

// ============ 2. ternarize (+inline stats finalize, +halo rows) ============
// tp chunk-major: [chunk][n][TPH][TPW][ci64] int8
__global__ void ternarize_kernel(const float* __restrict__ x,
                                 const double* __restrict__ part,
                                 const float* __restrict__ gamma,
                                 const float* __restrict__ beta,
                                 int8_t* __restrict__ tp) {
    __shared__ double scs[256], shs[256];
    __shared__ int8_t L[56 * 272];                  // [w][ci], stride 272 (16B-aligned)
    const int hp = blockIdx.x, n = blockIdx.y;      // hp in [0,58)
    const int tid = threadIdx.x;

    // per-block bitwise-identical stats finalize (one channel per thread)
    {
        const int c = tid;
        double S = 0.0, SS = 0.0;
#pragma unroll
        for (int sp = 0; sp < 8; ++sp) {
            S  += part[(sp * 256 + c) * 2];
            SS += part[(sp * 256 + c) * 2 + 1];
        }
        double mean = S / (double)CNT;
        double var  = SS / (double)CNT - mean * mean;
        double invstd = 1.0 / sqrt(var + 1e-4);
        double scale = (double)gamma[c] * invstd;
        scs[c] = scale;
        shs[c] = (double)beta[c] - mean * scale;
    }
    __syncthreads();

    const bool interior = (hp >= 1 && hp <= 56);
    if (interior) {
        const int h = hp - 1;
        const size_t xb = ((size_t)n * CI) * 3136 + (size_t)h * 56;
        for (int idx = tid; idx < CI * 14; idx += 256) {
            int ci = idx / 14, wq = idx - ci * 14;
            const float4 v = *(const float4*)(x + xb + (size_t)ci * 3136 + wq * 4);
            double sc = scs[ci], sh = shs[ci];
            L[(wq * 4 + 0) * 272 + ci] = (fma(sc, (double)v.x, sh) > 0.0) ? (int8_t)1 : (int8_t)-1;
            L[(wq * 4 + 1) * 272 + ci] = (fma(sc, (double)v.y, sh) > 0.0) ? (int8_t)1 : (int8_t)-1;
            L[(wq * 4 + 2) * 272 + ci] = (fma(sc, (double)v.z, sh) > 0.0) ? (int8_t)1 : (int8_t)-1;
            L[(wq * 4 + 3) * 272 + ci] = (fma(sc, (double)v.w, sh) > 0.0) ? (int8_t)1 : (int8_t)-1;
        }
    }
    __syncthreads();

    const size_t planeN = (size_t)NN * TPH * TPW * 64;
    for (int p = tid; p < TPW * 16; p += 256) {
        int wo = p >> 4, c16 = p & 15;
        int chunk = c16 >> 2, ci16 = c16 & 3;
        i32x4 v = {0, 0, 0, 0};
        if (interior && wo >= 1 && wo <= 56)
            v = *(const i32x4*)&L[(wo - 1) * 272 + c16 * 16];
        int8_t* dst = tp + chunk * planeN +
                      (((size_t)n * TPH + hp) * TPW + wo) * 64 + ci16 * 16;
        *(i32x4*)dst = v;
    }
}

// ============ 3. implicit-GEMM conv, int8 MFMA ============================
// grid (2, 28, 32); block 256 = 4 waves; tile 128co x (2 rows x 64w)
// B LDS per ci64-chunk: [row4][wp72][4 slots x 16B], ci16 slot XOR-rotated by wp.
__device__ __forceinline__ void stage_chunk(const int8_t* __restrict__ gc,
                                            int8_t* lbuf, int tid) {
#pragma unroll
    for (int j = 0; j < 5; ++j) {
        int p = tid + j * 256;                      // 0..1151
        if (j < 4 || tid < 128) {
            int row = p / 288, rem = p - row * 288;
            int wp = rem >> 2, s = rem & 3;
            int g = (s - wp) & 3;
            gld16(gc + (row * TPW + wp) * 64 + g * 16, lbuf + p * 16);
        }
    }
}

__launch_bounds__(256, 2)
__global__ void conv_kernel(const int8_t* __restrict__ wT,
                            const int8_t* __restrict__ tp,
                            const float* __restrict__ bias,
                            const float* __restrict__ qscale,
                            float* __restrict__ out) {
    const int co_t = blockIdx.x;
    const int h0   = blockIdx.y * 2;
    const int n    = blockIdx.z;
    const int tid  = threadIdx.x;
    const int lane = tid & 63, wid = tid >> 6;
    const int l15 = lane & 15, qd = lane >> 4;
    const int m_off = (wid & 1) * 64;
    const int rowsel = wid >> 1;
    const int cobase = co_t * 128 + m_off;

    __shared__ int8_t Bsh[2 * 4 * TPW * 64];        // 36864 B double-buffered

    i32x4 acc[4][4];
#pragma unroll
    for (int i = 0; i < 4; ++i)
#pragma unroll
        for (int j = 0; j < 4; ++j) acc[i][j] = (i32x4){0, 0, 0, 0};

    const size_t planeN = (size_t)NN * TPH * TPW * 64;
    const int8_t* g0 = tp + (((size_t)n * TPH + h0) * TPW) * 64;
    const i32x4* wbT = (const i32x4*)wT;

    stage_chunk(g0, Bsh, tid);
#pragma unroll
    for (int c = 0; c < 4; ++c) {
        __syncthreads();                            // stage(c) landed; buf (c-1) free
        // ---- hoist ALL a-frag loads for this chunk BEFORE next staging issue ----
        i32x4 aw[9][4];
#pragma unroll
        for (int t = 0; t < 9; ++t)
#pragma unroll
            for (int i = 0; i < 4; ++i)
                aw[t][i] = wbT[((size_t)((t * 4 + c) * 256) + cobase + i * 16 + l15) * 4 + qd];
        __builtin_amdgcn_sched_barrier(0);          // pin: a-loads issue before staging
        if (c < 3) stage_chunk(g0 + (size_t)(c + 1) * planeN,
                               Bsh + ((c + 1) & 1) * 18432, tid);
        const int8_t* lb = Bsh + (c & 1) * 18432;
#pragma unroll
        for (int kh = 0; kh < 3; ++kh) {
            const int brow = (rowsel + kh) * TPW;
#pragma unroll
            for (int kw = 0; kw < 3; ++kw) {
                const int tap = kh * 3 + kw;
                i32x4 b[4];
#pragma unroll
                for (int j = 0; j < 4; ++j) {
                    int wp = j * 16 + l15 + kw;
                    int slot = (qd + wp) & 3;
                    b[j] = *(const i32x4*)&lb[(brow + wp) * 64 + slot * 16];
                }
#pragma unroll
                for (int i = 0; i < 4; ++i)
#pragma unroll
                    for (int j = 0; j < 4; ++j)
                        acc[i][j] = __builtin_amdgcn_mfma_i32_16x16x64_i8(
                            aw[tap][i], b[j], acc[i][j], 0, 0, 0);
            }
        }
    }

    // epilogue: dequant + bias + relu, fp32 NCHW
    const int h_out = h0 + rowsel;
#pragma unroll
    for (int i = 0; i < 4; ++i) {
        const int co = cobase + i * 16 + qd * 4;
        const float4 bv = *(const float4*)&bias[co];
        const float4 qv = *(const float4*)&qscale[co];
        const float bb[4] = {bv.x, bv.y, bv.z, bv.w};
        const float qq[4] = {qv.x, qv.y, qv.z, qv.w};
#pragma unroll
        for (int j = 0; j < 4; ++j) {
            const int w = j * 16 + l15;
            if (w < 56) {
                const size_t ob = (((size_t)n * CO + co) * HH + h_out) * WW + w;
#pragma unroll
                for (int r = 0; r < 4; ++r) {
                    float v = (float)acc[i][j][r] * qq[r] + bb[r];
                    out[ob + (size_t)r * (HH * WW)] = v > 0.f ? v : 0.f;
                }
            }
        }
    }
}

// ================= launch =================
extern "C" void kernel_launch(void* const* d_in, const int* in_sizes, int n_in,
                              void* d_out, int out_size, void* d_ws, size_t ws_size,
                              hipStream_t stream) {
    const float* x      = (const float*)d_in[0];
    const float* gamma  = (const float*)d_in[1];
    const float* beta   = (const float*)d_in[2];
    const float* weight = (const float*)d_in[3];
    const float* bias   = (const float*)d_in[4];
    float* out = (float*)d_out;

    double* part    = (double*)d_ws;                            // 32768 B
    float*  qscale  = (float*) ((char*)d_ws + 32768);           // 1024 B
    int8_t* wT      = (int8_t*)((char*)d_ws + 65536);           // 589824 B
    int8_t* tp      = (int8_t*)((char*)d_ws + 1048576);         // 34209792 B

    prep_kernel<<<dim3(256, 9), 256, 0, stream>>>(x, weight, part, wT, qscale);
    ternarize_kernel<<<dim3(TPH, NN), 256, 0, stream>>>(x, part, gamma, beta, tp);
    conv_kernel<<<dim3(2, 28, NN), 256, 0, stream>>>(wT, tp, bias, qscale, out);
}